// Round 7
// baseline (94.928 us; speedup 1.0000x reference)
//
#include <hip/hip_runtime.h>
#include <hip/hip_bf16.h>
#include <math.h>

#define NN 50000
#define DD 128
#define ALPHA 0.1f
#define BETA 0.5f

typedef __attribute__((ext_vector_type(8))) short short8;   // bf16x8 MFMA frag
typedef __attribute__((ext_vector_type(4))) float floatx4;  // f32x4 accum

__device__ __forceinline__ float bf16lo(unsigned u) {
    return __uint_as_float(u << 16);
}
__device__ __forceinline__ float bf16hi(unsigned u) {
    return __uint_as_float(u & 0xffff0000u);
}
__device__ __forceinline__ unsigned pkbf(float a, float b) {
    unsigned la = (unsigned)__bfloat16_as_ushort(__float2bfloat16(a));
    unsigned lb = (unsigned)__bfloat16_as_ushort(__float2bfloat16(b));
    return la | (lb << 16);
}

// ---------------------------------------------------------------------------
// Kernel 1: prep = rowptr + h->bf16 + W->bf16 (fused, one launch).
// ---------------------------------------------------------------------------
__global__ __launch_bounds__(256) void prep_kernel(
    const int* __restrict__ edge_row, int E, int* __restrict__ rp,
    const float* __restrict__ h, ushort* __restrict__ hb,
    const float* __restrict__ W, ushort* __restrict__ wb)
{
    const int t = blockIdx.x * 256 + threadIdx.x;

    if (hb != nullptr && t < NN * DD / 4) {
        const float4 v = *reinterpret_cast<const float4*>(h + (size_t)t * 4);
        ushort4 o;
        o.x = __bfloat16_as_ushort(__float2bfloat16(v.x));
        o.y = __bfloat16_as_ushort(__float2bfloat16(v.y));
        o.z = __bfloat16_as_ushort(__float2bfloat16(v.z));
        o.w = __bfloat16_as_ushort(__float2bfloat16(v.w));
        *reinterpret_cast<ushort4*>(hb + (size_t)t * 4) = o;
    }

    if (wb != nullptr && t < DD * DD / 4) {
        const float4 v = *reinterpret_cast<const float4*>(W + (size_t)t * 4);
        ushort4 o;
        o.x = __bfloat16_as_ushort(__float2bfloat16(v.x));
        o.y = __bfloat16_as_ushort(__float2bfloat16(v.y));
        o.z = __bfloat16_as_ushort(__float2bfloat16(v.z));
        o.w = __bfloat16_as_ushort(__float2bfloat16(v.w));
        *reinterpret_cast<ushort4*>(wb + (size_t)t * 4) = o;
    }

    if (t <= E) {
        if (t == 0) {
            int r0 = edge_row[0];
            for (int r = 0; r <= r0; ++r) rp[r] = 0;
        } else if (t == E) {
            int rl = edge_row[E - 1];
            for (int r = rl + 1; r <= NN; ++r) rp[r] = E;
        } else {
            int rprev = edge_row[t - 1];
            int rcur  = edge_row[t];
            for (int r = rprev + 1; r <= rcur; ++r) rp[r] = t;
        }
    }
}

// ---------------------------------------------------------------------------
// Kernel 2: FUSED aggregate + MFMA linear + blend. 64 rows/block, 512 thr.
// Phase A (per wave, rows wave+8j): bf16 gather-aggregate -> LDS (sS fp32
//   for blend, sA bf16 for MFMA A). 16 edges / 4 gathers in flight.
// Phase B: wave w -> M-tile (w>>1)*16, N-half (w&1)*64. B-frags from global
//   bf16 W (L2-resident, row-major [out][in], k contiguous -> no transpose).
// C-layout (HW-verified in round 6): col=lane&15, row=(lane>>4)*4+reg.
// LDS: sS[64][132] f32 (33.8KB) + sA[64][136] bf16 (17.4KB) = 51.2KB -> 3/CU.
// ---------------------------------------------------------------------------
__global__ __launch_bounds__(512, 6) void fused_kernel(
    const ushort* __restrict__ hb, const float* __restrict__ h0,
    const int* __restrict__ edge_col, const float* __restrict__ edge_vals,
    const int* __restrict__ rp, const ushort* __restrict__ wb,
    const float* __restrict__ b, const int* __restrict__ lptr,
    float* __restrict__ out)
{
    __shared__ float  sS[64][132];
    __shared__ ushort sA[64][136];

    const int tid  = threadIdx.x;
    const int wave = tid >> 6;      // 0..7
    const int lane = tid & 63;
    const int g    = lane >> 4;     // edge slot 0..3
    const int li   = lane & 15;     // feature octet: li*8 .. li*8+7
    const int r0   = blockIdx.x * 64;

    const int lv = *lptr;
    const float theta  = logf(BETA / (float)lv + 1.0f);
    const float mtheta = 1.0f - theta;

    // ---------------- Phase A: aggregation into LDS ----------------
    for (int j = 0; j < 8; ++j) {
        const int ri = wave + 8 * j;
        const int r  = r0 + ri;

        float acc[8];
        #pragma unroll
        for (int q = 0; q < 8; ++q) acc[q] = 0.f;

        if (r < NN) {
            const int e0 = rp[r], e1 = rp[r + 1];
            for (int eb = e0; eb < e1; eb += 16) {
                #pragma unroll
                for (int u = 0; u < 4; ++u) {
                    const int e  = eb + u * 4 + g;
                    const int ee = min(e, e1 - 1);
                    const int   c = edge_col[ee];
                    const float v = (e < e1) ? edge_vals[ee] : 0.0f;
                    const uint4 hv = *reinterpret_cast<const uint4*>(
                        hb + (size_t)c * DD + li * 8);
                    acc[0] = fmaf(v, bf16lo(hv.x), acc[0]);
                    acc[1] = fmaf(v, bf16hi(hv.x), acc[1]);
                    acc[2] = fmaf(v, bf16lo(hv.y), acc[2]);
                    acc[3] = fmaf(v, bf16hi(hv.y), acc[3]);
                    acc[4] = fmaf(v, bf16lo(hv.z), acc[4]);
                    acc[5] = fmaf(v, bf16hi(hv.z), acc[5]);
                    acc[6] = fmaf(v, bf16lo(hv.w), acc[6]);
                    acc[7] = fmaf(v, bf16hi(hv.w), acc[7]);
                }
            }
        }

        #pragma unroll
        for (int q = 0; q < 8; ++q) {
            acc[q] += __shfl_xor(acc[q], 16);
            acc[q] += __shfl_xor(acc[q], 32);
        }

        if (g == 0) {
            float4 h0a = make_float4(0.f, 0.f, 0.f, 0.f);
            float4 h0b = make_float4(0.f, 0.f, 0.f, 0.f);
            if (r < NN) {
                h0a = *reinterpret_cast<const float4*>(h0 + (size_t)r * DD + li * 8);
                h0b = *reinterpret_cast<const float4*>(h0 + (size_t)r * DD + li * 8 + 4);
            }
            float4 oa, ob;
            oa.x = fmaf(1.0f - ALPHA, acc[0], ALPHA * h0a.x);
            oa.y = fmaf(1.0f - ALPHA, acc[1], ALPHA * h0a.y);
            oa.z = fmaf(1.0f - ALPHA, acc[2], ALPHA * h0a.z);
            oa.w = fmaf(1.0f - ALPHA, acc[3], ALPHA * h0a.w);
            ob.x = fmaf(1.0f - ALPHA, acc[4], ALPHA * h0b.x);
            ob.y = fmaf(1.0f - ALPHA, acc[5], ALPHA * h0b.y);
            ob.z = fmaf(1.0f - ALPHA, acc[6], ALPHA * h0b.z);
            ob.w = fmaf(1.0f - ALPHA, acc[7], ALPHA * h0b.w);
            *reinterpret_cast<float4*>(&sS[ri][li * 8])     = oa;
            *reinterpret_cast<float4*>(&sS[ri][li * 8 + 4]) = ob;
            uint4 pk;
            pk.x = pkbf(oa.x, oa.y);
            pk.y = pkbf(oa.z, oa.w);
            pk.z = pkbf(ob.x, ob.y);
            pk.w = pkbf(ob.z, ob.w);
            *reinterpret_cast<uint4*>(&sA[ri][li * 8]) = pk;
        }
    }
    __syncthreads();

    // ---------------- Phase B: MFMA linear ----------------
    const int m0 = (wave >> 1) * 16;     // M-tile base row in block
    const int nh = (wave & 1) * 64;      // N-half base col
    const int la = lane & 15;
    const int k0 = (lane >> 4) * 8;

    floatx4 facc[4];
    #pragma unroll
    for (int t = 0; t < 4; ++t) facc[t] = (floatx4){0.f, 0.f, 0.f, 0.f};

    #pragma unroll
    for (int s = 0; s < 4; ++s) {
        const int k = s * 32 + k0;
        const short8 af = *reinterpret_cast<const short8*>(&sA[m0 + la][k]);
        #pragma unroll
        for (int t = 0; t < 4; ++t) {
            const int col = nh + t * 16 + la;
            const short8 bf = *reinterpret_cast<const short8*>(
                wb + (size_t)col * DD + k);
            facc[t] = __builtin_amdgcn_mfma_f32_16x16x32_bf16(af, bf, facc[t], 0, 0, 0);
        }
    }

    // ---------------- epilogue: blend + store ----------------
    const int rg = (lane >> 4) * 4;
    #pragma unroll
    for (int t = 0; t < 4; ++t) {
        const int c  = nh + t * 16 + la;
        const float bb = b[c];
        #pragma unroll
        for (int jj = 0; jj < 4; ++jj) {
            const int rl = m0 + rg + jj;
            const int rr = r0 + rl;
            if (rr < NN) {
                out[(size_t)rr * DD + c] =
                    theta * (facc[t][jj] + bb) + mtheta * sS[rl][c];
            }
        }
    }
}

// ---------------------------------------------------------------------------
// Fallback path (ws too small): fp32 aggregation + fp32-vector linear.
// ---------------------------------------------------------------------------
__global__ __launch_bounds__(256, 6) void agg_fp32(
    const float* __restrict__ h, const float* __restrict__ h0,
    const int* __restrict__ edge_col, const float* __restrict__ edge_vals,
    const int* __restrict__ rp, float* __restrict__ io)
{
    const int wave = threadIdx.x >> 6;
    const int lane = threadIdx.x & 63;
    const int p    = lane >> 5;
    const int li   = lane & 31;
    const int r    = blockIdx.x * 4 + wave;
    if (r >= NN) return;

    const int e0 = rp[r], e1 = rp[r + 1];

    float4 A[4];
    #pragma unroll
    for (int u = 0; u < 4; ++u) A[u] = make_float4(0.f, 0.f, 0.f, 0.f);

    for (int eb = e0; eb < e1; eb += 8) {
        #pragma unroll
        for (int u = 0; u < 4; ++u) {
            const int e  = eb + 2 * u + p;
            const int ee = min(e, e1 - 1);
            const int   c = edge_col[ee];
            const float v = (e < e1) ? edge_vals[ee] : 0.0f;
            const float4 hv =
                *reinterpret_cast<const float4*>(h + (size_t)c * DD + li * 4);
            A[u].x = fmaf(v, hv.x, A[u].x);
            A[u].y = fmaf(v, hv.y, A[u].y);
            A[u].z = fmaf(v, hv.z, A[u].z);
            A[u].w = fmaf(v, hv.w, A[u].w);
        }
    }
    float4 s;
    s.x = (A[0].x + A[1].x) + (A[2].x + A[3].x);
    s.y = (A[0].y + A[1].y) + (A[2].y + A[3].y);
    s.z = (A[0].z + A[1].z) + (A[2].z + A[3].z);
    s.w = (A[0].w + A[1].w) + (A[2].w + A[3].w);
    s.x += __shfl_xor(s.x, 32);
    s.y += __shfl_xor(s.y, 32);
    s.z += __shfl_xor(s.z, 32);
    s.w += __shfl_xor(s.w, 32);

    if (p == 0) {
        const float4 h0v =
            *reinterpret_cast<const float4*>(h0 + (size_t)r * DD + li * 4);
        float4 sup;
        sup.x = fmaf(1.0f - ALPHA, s.x, ALPHA * h0v.x);
        sup.y = fmaf(1.0f - ALPHA, s.y, ALPHA * h0v.y);
        sup.z = fmaf(1.0f - ALPHA, s.z, ALPHA * h0v.z);
        sup.w = fmaf(1.0f - ALPHA, s.w, ALPHA * h0v.w);
        *reinterpret_cast<float4*>(io + (size_t)r * DD + li * 4) = sup;
    }
}

#define RPB 64
#define SPAD 132
#define WPAD 136

__global__ __launch_bounds__(512, 4) void lin_kernel(
    float* io, const float* __restrict__ W, const float* __restrict__ b,
    const int* __restrict__ lptr)
{
    __shared__ float sS[RPB][SPAD];
    __shared__ __hip_bfloat16 sWt[DD][WPAD];

    const int tid = threadIdx.x;
    const int r0  = blockIdx.x * RPB;
    const int tr  = tid >> 4;
    const int tc  = tid & 15;

    const int lv = *lptr;
    const float theta  = logf(BETA / (float)lv + 1.0f);
    const float mtheta = 1.0f - theta;

    for (int i = tid * 4; i < DD * DD; i += 512 * 4) {
        const float4 w4 = *reinterpret_cast<const float4*>(W + i);
        const int o = i >> 7;
        const int k = i & 127;
        sWt[k + 0][o] = __float2bfloat16(w4.x);
        sWt[k + 1][o] = __float2bfloat16(w4.y);
        sWt[k + 2][o] = __float2bfloat16(w4.z);
        sWt[k + 3][o] = __float2bfloat16(w4.w);
    }

    for (int idx = tid; idx < RPB * 32; idx += 512) {
        const int row = idx >> 5;
        const int q   = idx & 31;
        const int rr  = r0 + row;
        const float4 v = (rr < NN)
            ? *reinterpret_cast<const float4*>(io + (size_t)rr * DD + q * 4)
            : make_float4(0.f, 0.f, 0.f, 0.f);
        *reinterpret_cast<float4*>(&sS[row][q * 4]) = v;
    }
    __syncthreads();

    float acc[2][8];
    #pragma unroll
    for (int i = 0; i < 2; ++i)
        #pragma unroll
        for (int j = 0; j < 8; ++j) acc[i][j] = 0.f;

    for (int k = 0; k < DD; k += 4) {
        const float4 a0 = *reinterpret_cast<const float4*>(&sS[tr * 2 + 0][k]);
        const float4 a1 = *reinterpret_cast<const float4*>(&sS[tr * 2 + 1][k]);
        const float aa0[4] = {a0.x, a0.y, a0.z, a0.w};
        const float aa1[4] = {a1.x, a1.y, a1.z, a1.w};
        #pragma unroll
        for (int kk = 0; kk < 4; ++kk) {
            const uint4 wr = *reinterpret_cast<const uint4*>(&sWt[k + kk][tc * 8]);
            float w[8];
            w[0] = bf16lo(wr.x); w[1] = bf16hi(wr.x);
            w[2] = bf16lo(wr.y); w[3] = bf16hi(wr.y);
            w[4] = bf16lo(wr.z); w[5] = bf16hi(wr.z);
            w[6] = bf16lo(wr.w); w[7] = bf16hi(wr.w);
            #pragma unroll
            for (int j = 0; j < 8; ++j) {
                acc[0][j] = fmaf(aa0[kk], w[j], acc[0][j]);
                acc[1][j] = fmaf(aa1[kk], w[j], acc[1][j]);
            }
        }
    }

    #pragma unroll
    for (int i = 0; i < 2; ++i) {
        const int ri = tr * 2 + i;
        const int rr = r0 + ri;
        if (rr >= NN) continue;
        #pragma unroll
        for (int j4 = 0; j4 < 2; ++j4) {
            const int cc = tc * 8 + j4 * 4;
            const float4 bv  = *reinterpret_cast<const float4*>(&b[cc]);
            const float4 sup = *reinterpret_cast<const float4*>(&sS[ri][cc]);
            float4 o4;
            o4.x = theta * (acc[i][j4 * 4 + 0] + bv.x) + mtheta * sup.x;
            o4.y = theta * (acc[i][j4 * 4 + 1] + bv.y) + mtheta * sup.y;
            o4.z = theta * (acc[i][j4 * 4 + 2] + bv.z) + mtheta * sup.z;
            o4.w = theta * (acc[i][j4 * 4 + 3] + bv.w) + mtheta * sup.w;
            *reinterpret_cast<float4*>(io + (size_t)rr * DD + cc) = o4;
        }
    }
}

extern "C" void kernel_launch(void* const* d_in, const int* in_sizes, int n_in,
                              void* d_out, int out_size, void* d_ws, size_t ws_size,
                              hipStream_t stream) {
    const float* h         = (const float*)d_in[0];
    const float* h0        = (const float*)d_in[1];
    const int*   edge_row  = (const int*)d_in[2];
    const int*   edge_col  = (const int*)d_in[3];
    const float* edge_vals = (const float*)d_in[4];
    const float* W         = (const float*)d_in[5];
    const float* b         = (const float*)d_in[6];
    const int*   lptr      = (const int*)d_in[7];
    const int E = in_sizes[2];

    // ws layout: rp (256KB) | hb bf16 h (12.8MB) | wb bf16 W (32KB)
    char* wsb = (char*)d_ws;
    int*    rp = (int*)wsb;
    ushort* hb = (ushort*)(wsb + (1 << 18));
    ushort* wb = (ushort*)(wsb + (1 << 18) + (size_t)NN * DD * sizeof(ushort));
    float*  io = (float*)d_out;

    const size_t need = (size_t)(1 << 18)
                      + (size_t)NN * DD * sizeof(ushort)
                      + (size_t)DD * DD * sizeof(ushort);
    const bool fast = (ws_size >= need);

    const int convT = NN * DD / 4;  // 1.6M threads (covers E+1 and W conv)
    const int gridP = (convT + 255) / 256;
    prep_kernel<<<gridP, 256, 0, stream>>>(edge_row, E, rp, h,
                                           fast ? hb : nullptr,
                                           W, fast ? wb : nullptr);

    if (fast) {
        fused_kernel<<<(NN + 63) / 64, 512, 0, stream>>>(
            hb, h0, edge_col, edge_vals, rp, wb, b, lptr, io);
    } else {
        agg_fp32<<<(NN + 3) / 4, 256, 0, stream>>>(h, h0, edge_col, edge_vals, rp, io);
        lin_kernel<<<(NN + RPB - 1) / RPB, 512, 0, stream>>>(io, W, b, lptr);
    }
}

// Round 8
// 79.513 us; speedup vs baseline: 1.1939x; 1.1939x over previous
//
#include <hip/hip_runtime.h>
#include <hip/hip_bf16.h>
#include <math.h>

#define NN 50000
#define DD 128
#define ALPHA 0.1f
#define BETA 0.5f

typedef __attribute__((ext_vector_type(8))) short short8;   // bf16x8 MFMA frag
typedef __attribute__((ext_vector_type(4))) float floatx4;  // f32x4 accum
typedef _Float16 h2 __attribute__((ext_vector_type(2)));    // packed f16 pair

__device__ __forceinline__ float bf16lo(unsigned u) {
    return __uint_as_float(u << 16);
}
__device__ __forceinline__ float bf16hi(unsigned u) {
    return __uint_as_float(u & 0xffff0000u);
}
__device__ __forceinline__ unsigned pkbf(float a, float b) {
    unsigned la = (unsigned)__bfloat16_as_ushort(__float2bfloat16(a));
    unsigned lb = (unsigned)__bfloat16_as_ushort(__float2bfloat16(b));
    return la | (lb << 16);
}
__device__ __forceinline__ unsigned pkh(float a, float b) {
    h2 p = {(_Float16)a, (_Float16)b};
    return __builtin_bit_cast(unsigned, p);
}
__device__ __forceinline__ h2 as_h2(unsigned u) {
    return __builtin_bit_cast(h2, u);
}

// ---------------------------------------------------------------------------
// Kernel 1: prep = rowptr + h->f16 (8/thread) + W->bf16.
// Grid covers max(NN*DD/8, E+1) threads.
// ---------------------------------------------------------------------------
__global__ __launch_bounds__(256) void prep_kernel(
    const int* __restrict__ edge_row, int E, int* __restrict__ rp,
    const float* __restrict__ h, ushort* __restrict__ hh,
    const float* __restrict__ W, ushort* __restrict__ wb)
{
    const int t = blockIdx.x * 256 + threadIdx.x;

    if (hh != nullptr && t < NN * DD / 8) {
        const float4 v0 = *reinterpret_cast<const float4*>(h + (size_t)t * 8);
        const float4 v1 = *reinterpret_cast<const float4*>(h + (size_t)t * 8 + 4);
        uint4 o;
        o.x = pkh(v0.x, v0.y);
        o.y = pkh(v0.z, v0.w);
        o.z = pkh(v1.x, v1.y);
        o.w = pkh(v1.z, v1.w);
        *reinterpret_cast<uint4*>(hh + (size_t)t * 8) = o;
    }

    if (wb != nullptr && t < DD * DD / 4) {
        const float4 v = *reinterpret_cast<const float4*>(W + (size_t)t * 4);
        ushort4 o;
        o.x = __bfloat16_as_ushort(__float2bfloat16(v.x));
        o.y = __bfloat16_as_ushort(__float2bfloat16(v.y));
        o.z = __bfloat16_as_ushort(__float2bfloat16(v.z));
        o.w = __bfloat16_as_ushort(__float2bfloat16(v.w));
        *reinterpret_cast<ushort4*>(wb + (size_t)t * 4) = o;
    }

    if (t <= E) {
        if (t == 0) {
            int r0 = edge_row[0];
            for (int r = 0; r <= r0; ++r) rp[r] = 0;
        } else if (t == E) {
            int rl = edge_row[E - 1];
            for (int r = rl + 1; r <= NN; ++r) rp[r] = E;
        } else {
            int rprev = edge_row[t - 1];
            int rcur  = edge_row[t];
            for (int r = rprev + 1; r <= rcur; ++r) rp[r] = t;
        }
    }
}

// ---------------------------------------------------------------------------
// Kernel 2a: f16-gather aggregation with packed v_pk_fma_f16 accumulation.
//   io[r] = 0.9 * sum_e val[e]*hh[col[e]] + 0.1 * h0[r]
// One wave per row, no LDS. g = lane>>4 (edge slot), li = lane&15
// (features li*8..+7 as uint4 = 8 f16). 4-way unroll -> 16 edges / 4
// independent gathers in flight. Accum in 4x h2 (8 f16), f32 finish.
// ---------------------------------------------------------------------------
__global__ __launch_bounds__(256, 8) void agg_f16(
    const ushort* __restrict__ hh, const float* __restrict__ h0,
    const int* __restrict__ edge_col, const float* __restrict__ edge_vals,
    const int* __restrict__ rp, float* __restrict__ io)
{
    const int wave = threadIdx.x >> 6;
    const int lane = threadIdx.x & 63;
    const int g    = lane >> 4;
    const int li   = lane & 15;
    const int r    = blockIdx.x * 4 + wave;
    if (r >= NN) return;

    const int e0 = rp[r], e1 = rp[r + 1];

    h2 a0 = {0, 0}, a1 = {0, 0}, a2 = {0, 0}, a3 = {0, 0};

    for (int eb = e0; eb < e1; eb += 16) {
        #pragma unroll
        for (int u = 0; u < 4; ++u) {
            const int e  = eb + u * 4 + g;
            const int ee = min(e, e1 - 1);
            const int   c = edge_col[ee];
            const float v = (e < e1) ? edge_vals[ee] : 0.0f;
            const uint4 hv = *reinterpret_cast<const uint4*>(
                hh + (size_t)c * DD + li * 8);
            const _Float16 vh = (_Float16)v;
            const h2 vv = {vh, vh};
            a0 += as_h2(hv.x) * vv;   // v_pk_fma_f16
            a1 += as_h2(hv.y) * vv;
            a2 += as_h2(hv.z) * vv;
            a3 += as_h2(hv.w) * vv;
        }
    }

    float acc[8];
    acc[0] = (float)a0.x; acc[1] = (float)a0.y;
    acc[2] = (float)a1.x; acc[3] = (float)a1.y;
    acc[4] = (float)a2.x; acc[5] = (float)a2.y;
    acc[6] = (float)a3.x; acc[7] = (float)a3.y;

    #pragma unroll
    for (int j = 0; j < 8; ++j) {
        acc[j] += __shfl_xor(acc[j], 16);
        acc[j] += __shfl_xor(acc[j], 32);
    }

    if (g == 0) {
        const float4 h0a = *reinterpret_cast<const float4*>(
            h0 + (size_t)r * DD + li * 8);
        const float4 h0b = *reinterpret_cast<const float4*>(
            h0 + (size_t)r * DD + li * 8 + 4);
        float4 oa, ob;
        oa.x = fmaf(1.0f - ALPHA, acc[0], ALPHA * h0a.x);
        oa.y = fmaf(1.0f - ALPHA, acc[1], ALPHA * h0a.y);
        oa.z = fmaf(1.0f - ALPHA, acc[2], ALPHA * h0a.z);
        oa.w = fmaf(1.0f - ALPHA, acc[3], ALPHA * h0a.w);
        ob.x = fmaf(1.0f - ALPHA, acc[4], ALPHA * h0b.x);
        ob.y = fmaf(1.0f - ALPHA, acc[5], ALPHA * h0b.y);
        ob.z = fmaf(1.0f - ALPHA, acc[6], ALPHA * h0b.z);
        ob.w = fmaf(1.0f - ALPHA, acc[7], ALPHA * h0b.w);
        *reinterpret_cast<float4*>(io + (size_t)r * DD + li * 8)     = oa;
        *reinterpret_cast<float4*>(io + (size_t)r * DD + li * 8 + 4) = ob;
    }
}

// ---------------------------------------------------------------------------
// Kernel 3a: MFMA linear+blend (round-6-proven, unchanged).
//   out = theta*(sup @ W^T + b) + (1-theta)*sup, in place on io.
// C-layout (HW-verified): col=lane&15, row=(lane>>4)*4+reg.
// ---------------------------------------------------------------------------
__global__ __launch_bounds__(256, 3) void lin_mfma(
    float* io, const ushort* __restrict__ wb, const float* __restrict__ b,
    const int* __restrict__ lptr)
{
    __shared__ float  sS[64][132];
    __shared__ ushort sA[64][136];

    const int tid = threadIdx.x;
    const int r0  = blockIdx.x * 64;

    const int lv = *lptr;
    const float theta  = logf(BETA / (float)lv + 1.0f);
    const float mtheta = 1.0f - theta;

    for (int idx = tid; idx < 64 * 16; idx += 256) {
        const int row = idx >> 4;
        const int c8  = (idx & 15) * 8;
        const int rr  = r0 + row;
        float4 v0 = make_float4(0.f, 0.f, 0.f, 0.f);
        float4 v1 = make_float4(0.f, 0.f, 0.f, 0.f);
        if (rr < NN) {
            v0 = *reinterpret_cast<const float4*>(io + (size_t)rr * DD + c8);
            v1 = *reinterpret_cast<const float4*>(io + (size_t)rr * DD + c8 + 4);
        }
        *reinterpret_cast<float4*>(&sS[row][c8])     = v0;
        *reinterpret_cast<float4*>(&sS[row][c8 + 4]) = v1;
        uint4 pk;
        pk.x = pkbf(v0.x, v0.y);
        pk.y = pkbf(v0.z, v0.w);
        pk.z = pkbf(v1.x, v1.y);
        pk.w = pkbf(v1.z, v1.w);
        *reinterpret_cast<uint4*>(&sA[row][c8]) = pk;
    }
    __syncthreads();

    const int wave = tid >> 6;
    const int lane = tid & 63;
    const int m0   = wave * 16;
    const int la   = lane & 15;
    const int k0   = (lane >> 4) * 8;

    floatx4 acc[8];
    #pragma unroll
    for (int t = 0; t < 8; ++t) acc[t] = (floatx4){0.f, 0.f, 0.f, 0.f};

    #pragma unroll
    for (int s = 0; s < 4; ++s) {
        const int k = s * 32 + k0;
        const short8 af = *reinterpret_cast<const short8*>(&sA[m0 + la][k]);
        #pragma unroll
        for (int t = 0; t < 8; ++t) {
            const int col = t * 16 + la;
            const short8 bf = *reinterpret_cast<const short8*>(
                wb + (size_t)col * DD + k);
            acc[t] = __builtin_amdgcn_mfma_f32_16x16x32_bf16(af, bf, acc[t], 0, 0, 0);
        }
    }

    const int rg = (lane >> 4) * 4;
    #pragma unroll
    for (int t = 0; t < 8; ++t) {
        const int c  = t * 16 + la;
        const float bb = b[c];
        #pragma unroll
        for (int j = 0; j < 4; ++j) {
            const int rl = m0 + rg + j;
            const int rr = r0 + rl;
            if (rr < NN) {
                const float sup = sS[rl][c];
                io[(size_t)rr * DD + c] =
                    theta * (acc[t][j] + bb) + mtheta * sup;
            }
        }
    }
}

// ---------------------------------------------------------------------------
// Fallback path (ws too small): fp32 aggregation + fp32-vector linear.
// ---------------------------------------------------------------------------
__global__ __launch_bounds__(256, 6) void agg_fp32(
    const float* __restrict__ h, const float* __restrict__ h0,
    const int* __restrict__ edge_col, const float* __restrict__ edge_vals,
    const int* __restrict__ rp, float* __restrict__ io)
{
    const int wave = threadIdx.x >> 6;
    const int lane = threadIdx.x & 63;
    const int p    = lane >> 5;
    const int li   = lane & 31;
    const int r    = blockIdx.x * 4 + wave;
    if (r >= NN) return;

    const int e0 = rp[r], e1 = rp[r + 1];

    float4 A[4];
    #pragma unroll
    for (int u = 0; u < 4; ++u) A[u] = make_float4(0.f, 0.f, 0.f, 0.f);

    for (int eb = e0; eb < e1; eb += 8) {
        #pragma unroll
        for (int u = 0; u < 4; ++u) {
            const int e  = eb + 2 * u + p;
            const int ee = min(e, e1 - 1);
            const int   c = edge_col[ee];
            const float v = (e < e1) ? edge_vals[ee] : 0.0f;
            const float4 hv =
                *reinterpret_cast<const float4*>(h + (size_t)c * DD + li * 4);
            A[u].x = fmaf(v, hv.x, A[u].x);
            A[u].y = fmaf(v, hv.y, A[u].y);
            A[u].z = fmaf(v, hv.z, A[u].z);
            A[u].w = fmaf(v, hv.w, A[u].w);
        }
    }
    float4 s;
    s.x = (A[0].x + A[1].x) + (A[2].x + A[3].x);
    s.y = (A[0].y + A[1].y) + (A[2].y + A[3].y);
    s.z = (A[0].z + A[1].z) + (A[2].z + A[3].z);
    s.w = (A[0].w + A[1].w) + (A[2].w + A[3].w);
    s.x += __shfl_xor(s.x, 32);
    s.y += __shfl_xor(s.y, 32);
    s.z += __shfl_xor(s.z, 32);
    s.w += __shfl_xor(s.w, 32);

    if (p == 0) {
        const float4 h0v =
            *reinterpret_cast<const float4*>(h0 + (size_t)r * DD + li * 4);
        float4 sup;
        sup.x = fmaf(1.0f - ALPHA, s.x, ALPHA * h0v.x);
        sup.y = fmaf(1.0f - ALPHA, s.y, ALPHA * h0v.y);
        sup.z = fmaf(1.0f - ALPHA, s.z, ALPHA * h0v.z);
        sup.w = fmaf(1.0f - ALPHA, s.w, ALPHA * h0v.w);
        *reinterpret_cast<float4*>(io + (size_t)r * DD + li * 4) = sup;
    }
}

#define RPB 64
#define SPAD 132
#define WPAD 136

__global__ __launch_bounds__(512, 4) void lin_kernel(
    float* io, const float* __restrict__ W, const float* __restrict__ b,
    const int* __restrict__ lptr)
{
    __shared__ float sS[RPB][SPAD];
    __shared__ __hip_bfloat16 sWt[DD][WPAD];

    const int tid = threadIdx.x;
    const int r0  = blockIdx.x * RPB;
    const int tr  = tid >> 4;
    const int tc  = tid & 15;

    const int lv = *lptr;
    const float theta  = logf(BETA / (float)lv + 1.0f);
    const float mtheta = 1.0f - theta;

    for (int i = tid * 4; i < DD * DD; i += 512 * 4) {
        const float4 w4 = *reinterpret_cast<const float4*>(W + i);
        const int o = i >> 7;
        const int k = i & 127;
        sWt[k + 0][o] = __float2bfloat16(w4.x);
        sWt[k + 1][o] = __float2bfloat16(w4.y);
        sWt[k + 2][o] = __float2bfloat16(w4.z);
        sWt[k + 3][o] = __float2bfloat16(w4.w);
    }

    for (int idx = tid; idx < RPB * 32; idx += 512) {
        const int row = idx >> 5;
        const int q   = idx & 31;
        const int rr  = r0 + row;
        const float4 v = (rr < NN)
            ? *reinterpret_cast<const float4*>(io + (size_t)rr * DD + q * 4)
            : make_float4(0.f, 0.f, 0.f, 0.f);
        *reinterpret_cast<float4*>(&sS[row][q * 4]) = v;
    }
    __syncthreads();

    float acc[2][8];
    #pragma unroll
    for (int i = 0; i < 2; ++i)
        #pragma unroll
        for (int j = 0; j < 8; ++j) acc[i][j] = 0.f;

    for (int k = 0; k < DD; k += 4) {
        const float4 a0 = *reinterpret_cast<const float4*>(&sS[tr * 2 + 0][k]);
        const float4 a1 = *reinterpret_cast<const float4*>(&sS[tr * 2 + 1][k]);
        const float aa0[4] = {a0.x, a0.y, a0.z, a0.w};
        const float aa1[4] = {a1.x, a1.y, a1.z, a1.w};
        #pragma unroll
        for (int kk = 0; kk < 4; ++kk) {
            const uint4 wr = *reinterpret_cast<const uint4*>(&sWt[k + kk][tc * 8]);
            float w[8];
            w[0] = bf16lo(wr.x); w[1] = bf16hi(wr.x);
            w[2] = bf16lo(wr.y); w[3] = bf16hi(wr.y);
            w[4] = bf16lo(wr.z); w[5] = bf16hi(wr.z);
            w[6] = bf16lo(wr.w); w[7] = bf16hi(wr.w);
            #pragma unroll
            for (int j = 0; j < 8; ++j) {
                acc[0][j] = fmaf(aa0[kk], w[j], acc[0][j]);
                acc[1][j] = fmaf(aa1[kk], w[j], acc[1][j]);
            }
        }
    }

    #pragma unroll
    for (int i = 0; i < 2; ++i) {
        const int ri = tr * 2 + i;
        const int rr = r0 + ri;
        if (rr >= NN) continue;
        #pragma unroll
        for (int j4 = 0; j4 < 2; ++j4) {
            const int cc = tc * 8 + j4 * 4;
            const float4 bv  = *reinterpret_cast<const float4*>(&b[cc]);
            const float4 sup = *reinterpret_cast<const float4*>(&sS[ri][cc]);
            float4 o4;
            o4.x = theta * (acc[i][j4 * 4 + 0] + bv.x) + mtheta * sup.x;
            o4.y = theta * (acc[i][j4 * 4 + 1] + bv.y) + mtheta * sup.y;
            o4.z = theta * (acc[i][j4 * 4 + 2] + bv.z) + mtheta * sup.z;
            o4.w = theta * (acc[i][j4 * 4 + 3] + bv.w) + mtheta * sup.w;
            *reinterpret_cast<float4*>(io + (size_t)rr * DD + cc) = o4;
        }
    }
}

extern "C" void kernel_launch(void* const* d_in, const int* in_sizes, int n_in,
                              void* d_out, int out_size, void* d_ws, size_t ws_size,
                              hipStream_t stream) {
    const float* h         = (const float*)d_in[0];
    const float* h0        = (const float*)d_in[1];
    const int*   edge_row  = (const int*)d_in[2];
    const int*   edge_col  = (const int*)d_in[3];
    const float* edge_vals = (const float*)d_in[4];
    const float* W         = (const float*)d_in[5];
    const float* b         = (const float*)d_in[6];
    const int*   lptr      = (const int*)d_in[7];
    const int E = in_sizes[2];

    // ws layout: rp (256KB) | hh f16 h (12.8MB) | wb bf16 W (32KB)
    char* wsb = (char*)d_ws;
    int*    rp = (int*)wsb;
    ushort* hh = (ushort*)(wsb + (1 << 18));
    ushort* wb = (ushort*)(wsb + (1 << 18) + (size_t)NN * DD * sizeof(ushort));
    float*  io = (float*)d_out;

    const size_t need = (size_t)(1 << 18)
                      + (size_t)NN * DD * sizeof(ushort)
                      + (size_t)DD * DD * sizeof(ushort);
    const bool fast = (ws_size >= need);

    // grid covers max(h-conv threads, E+1) = max(800000, 800001)
    const int nT = (NN * DD / 8 > E + 1) ? NN * DD / 8 : E + 1;
    prep_kernel<<<(nT + 255) / 256, 256, 0, stream>>>(
        edge_row, E, rp, h, fast ? hh : nullptr, W, fast ? wb : nullptr);

    if (fast) {
        agg_f16<<<(NN + 3) / 4, 256, 0, stream>>>(hh, h0, edge_col, edge_vals, rp, io);
        lin_mfma<<<(NN + 63) / 64, 256, 0, stream>>>(io, wb, b, lptr);
    } else {
        agg_fp32<<<(NN + 3) / 4, 256, 0, stream>>>(h, h0, edge_col, edge_vals, rp, io);
        lin_kernel<<<(NN + RPB - 1) / RPB, 512, 0, stream>>>(io, W, b, lptr);
    }
}

// Round 9
// 76.398 us; speedup vs baseline: 1.2425x; 1.0408x over previous
//
#include <hip/hip_runtime.h>
#include <hip/hip_bf16.h>
#include <math.h>

#define NN 50000
#define DD 128
#define ALPHA 0.1f
#define BETA 0.5f

typedef __attribute__((ext_vector_type(8))) short short8;   // 8x16b MFMA frag
typedef __attribute__((ext_vector_type(4))) float floatx4;  // f32x4 accum
typedef _Float16 h2 __attribute__((ext_vector_type(2)));    // packed f16 pair

__device__ __forceinline__ float bf16lo(unsigned u) {
    return __uint_as_float(u << 16);
}
__device__ __forceinline__ float bf16hi(unsigned u) {
    return __uint_as_float(u & 0xffff0000u);
}
__device__ __forceinline__ unsigned pkbf(float a, float b) {
    unsigned la = (unsigned)__bfloat16_as_ushort(__float2bfloat16(a));
    unsigned lb = (unsigned)__bfloat16_as_ushort(__float2bfloat16(b));
    return la | (lb << 16);
}
__device__ __forceinline__ unsigned pkh(float a, float b) {
    h2 p = {(_Float16)a, (_Float16)b};
    return __builtin_bit_cast(unsigned, p);
}
__device__ __forceinline__ h2 as_h2(unsigned u) {
    return __builtin_bit_cast(h2, u);
}

// ---------------------------------------------------------------------------
// Kernel 1: prep = rowptr + h->f16 + W->{f16,bf16}.
// ---------------------------------------------------------------------------
__global__ __launch_bounds__(256) void prep_kernel(
    const int* __restrict__ edge_row, int E, int* __restrict__ rp,
    const float* __restrict__ h, ushort* __restrict__ hh,
    const float* __restrict__ W, ushort* __restrict__ wf,
    ushort* __restrict__ wbf)
{
    const int t = blockIdx.x * 256 + threadIdx.x;

    if (hh != nullptr && t < NN * DD / 8) {
        const float4 v0 = *reinterpret_cast<const float4*>(h + (size_t)t * 8);
        const float4 v1 = *reinterpret_cast<const float4*>(h + (size_t)t * 8 + 4);
        uint4 o;
        o.x = pkh(v0.x, v0.y);
        o.y = pkh(v0.z, v0.w);
        o.z = pkh(v1.x, v1.y);
        o.w = pkh(v1.z, v1.w);
        *reinterpret_cast<uint4*>(hh + (size_t)t * 8) = o;
    }

    if (wf != nullptr && t < DD * DD / 4) {
        const float4 v = *reinterpret_cast<const float4*>(W + (size_t)t * 4);
        uint2 of;
        of.x = pkh(v.x, v.y);
        of.y = pkh(v.z, v.w);
        *reinterpret_cast<uint2*>(wf + (size_t)t * 4) = of;
        uint2 ob;
        ob.x = pkbf(v.x, v.y);
        ob.y = pkbf(v.z, v.w);
        *reinterpret_cast<uint2*>(wbf + (size_t)t * 4) = ob;
    }

    if (t <= E) {
        if (t == 0) {
            int r0 = edge_row[0];
            for (int r = 0; r <= r0; ++r) rp[r] = 0;
        } else if (t == E) {
            int rl = edge_row[E - 1];
            for (int r = rl + 1; r <= NN; ++r) rp[r] = E;
        } else {
            int rprev = edge_row[t - 1];
            int rcur  = edge_row[t];
            for (int r = rprev + 1; r <= rcur; ++r) rp[r] = t;
        }
    }
}

// ---------------------------------------------------------------------------
// Kernel 2 (tier2): pure gather-aggregate, NO h0, f16 output.
//   hib[r] = sum_e val[e] * hh[col[e]]   (raw hi, f16)
// One wave per row. g = lane>>4 (edge slot), li = lane&15 (features li*8..+7).
// 4-way unroll -> 16 edges / 4 independent gathers in flight.
// ---------------------------------------------------------------------------
__global__ __launch_bounds__(256, 8) void agg2(
    const ushort* __restrict__ hh,
    const int* __restrict__ edge_col, const float* __restrict__ edge_vals,
    const int* __restrict__ rp, ushort* __restrict__ hib)
{
    const int wave = threadIdx.x >> 6;
    const int lane = threadIdx.x & 63;
    const int g    = lane >> 4;
    const int li   = lane & 15;
    const int r    = blockIdx.x * 4 + wave;
    if (r >= NN) return;

    const int e0 = rp[r], e1 = rp[r + 1];

    h2 a0 = {0, 0}, a1 = {0, 0}, a2 = {0, 0}, a3 = {0, 0};

    for (int eb = e0; eb < e1; eb += 16) {
        #pragma unroll
        for (int u = 0; u < 4; ++u) {
            const int e  = eb + u * 4 + g;
            const int ee = min(e, e1 - 1);
            const int   c = edge_col[ee];
            const float v = (e < e1) ? edge_vals[ee] : 0.0f;
            const uint4 hv = *reinterpret_cast<const uint4*>(
                hh + (size_t)c * DD + li * 8);
            const _Float16 vh = (_Float16)v;
            const h2 vv = {vh, vh};
            a0 += as_h2(hv.x) * vv;
            a1 += as_h2(hv.y) * vv;
            a2 += as_h2(hv.z) * vv;
            a3 += as_h2(hv.w) * vv;
        }
    }

    float acc[8];
    acc[0] = (float)a0.x; acc[1] = (float)a0.y;
    acc[2] = (float)a1.x; acc[3] = (float)a1.y;
    acc[4] = (float)a2.x; acc[5] = (float)a2.y;
    acc[6] = (float)a3.x; acc[7] = (float)a3.y;

    #pragma unroll
    for (int j = 0; j < 8; ++j) {
        acc[j] += __shfl_xor(acc[j], 16);
        acc[j] += __shfl_xor(acc[j], 32);
    }

    if (g == 0) {
        uint4 o;
        o.x = pkh(acc[0], acc[1]);
        o.y = pkh(acc[2], acc[3]);
        o.z = pkh(acc[4], acc[5]);
        o.w = pkh(acc[6], acc[7]);
        *reinterpret_cast<uint4*>(hib + (size_t)r * DD + li * 8) = o;
    }
}

// ---------------------------------------------------------------------------
// Kernel 3 (tier2): blend + f16 MFMA linear.
//   sup = 0.9*hi + 0.1*h0 (fp32, from f16 hi + fp32 h0)
//   out = theta*(sup @ W^T + b) + (1-theta)*sup
// 64 rows/block, 256 thr (4 waves), wave w -> M-tile w*16, 8 col-tiles.
// C-layout (HW-verified): col=lane&15, row=(lane>>4)*4+reg.
// LDS: sS f32 [64][132] 33.8KB + sA f16 [64][136] 17.4KB = 51.2KB -> 3/CU.
// ---------------------------------------------------------------------------
__global__ __launch_bounds__(256, 3) void lin2(
    const ushort* __restrict__ hib, const float* __restrict__ h0,
    const ushort* __restrict__ wf, const float* __restrict__ b,
    const int* __restrict__ lptr, float* __restrict__ out)
{
    __shared__ float  sS[64][132];
    __shared__ ushort sA[64][136];

    const int tid = threadIdx.x;
    const int r0  = blockIdx.x * 64;

    const int lv = *lptr;
    const float theta  = logf(BETA / (float)lv + 1.0f);
    const float mtheta = 1.0f - theta;

    // --- stage: hi(f16) + h0(f32) -> sup: fp32 sS + f16 sA ---
    for (int idx = tid; idx < 64 * 16; idx += 256) {
        const int row = idx >> 4;
        const int c8  = (idx & 15) * 8;
        const int rr  = r0 + row;
        float sup[8];
        if (rr < NN) {
            const uint4 hv = *reinterpret_cast<const uint4*>(
                hib + (size_t)rr * DD + c8);
            const float4 h0a = *reinterpret_cast<const float4*>(
                h0 + (size_t)rr * DD + c8);
            const float4 h0b = *reinterpret_cast<const float4*>(
                h0 + (size_t)rr * DD + c8 + 4);
            const h2 p0 = as_h2(hv.x), p1 = as_h2(hv.y);
            const h2 p2 = as_h2(hv.z), p3 = as_h2(hv.w);
            sup[0] = fmaf(1.0f - ALPHA, (float)p0.x, ALPHA * h0a.x);
            sup[1] = fmaf(1.0f - ALPHA, (float)p0.y, ALPHA * h0a.y);
            sup[2] = fmaf(1.0f - ALPHA, (float)p1.x, ALPHA * h0a.z);
            sup[3] = fmaf(1.0f - ALPHA, (float)p1.y, ALPHA * h0a.w);
            sup[4] = fmaf(1.0f - ALPHA, (float)p2.x, ALPHA * h0b.x);
            sup[5] = fmaf(1.0f - ALPHA, (float)p2.y, ALPHA * h0b.y);
            sup[6] = fmaf(1.0f - ALPHA, (float)p3.x, ALPHA * h0b.z);
            sup[7] = fmaf(1.0f - ALPHA, (float)p3.y, ALPHA * h0b.w);
        } else {
            #pragma unroll
            for (int q = 0; q < 8; ++q) sup[q] = 0.f;
        }
        *reinterpret_cast<float4*>(&sS[row][c8]) =
            make_float4(sup[0], sup[1], sup[2], sup[3]);
        *reinterpret_cast<float4*>(&sS[row][c8 + 4]) =
            make_float4(sup[4], sup[5], sup[6], sup[7]);
        uint4 pk;
        pk.x = pkh(sup[0], sup[1]);
        pk.y = pkh(sup[2], sup[3]);
        pk.z = pkh(sup[4], sup[5]);
        pk.w = pkh(sup[6], sup[7]);
        *reinterpret_cast<uint4*>(&sA[row][c8]) = pk;
    }
    __syncthreads();

    const int wave = tid >> 6;
    const int lane = tid & 63;
    const int m0   = wave * 16;
    const int la   = lane & 15;
    const int k0   = (lane >> 4) * 8;

    floatx4 acc[8];
    #pragma unroll
    for (int t = 0; t < 8; ++t) acc[t] = (floatx4){0.f, 0.f, 0.f, 0.f};

    #pragma unroll
    for (int s = 0; s < 4; ++s) {
        const int k = s * 32 + k0;
        const short8 af = *reinterpret_cast<const short8*>(&sA[m0 + la][k]);
        #pragma unroll
        for (int t = 0; t < 8; ++t) {
            const int col = t * 16 + la;
            const short8 bf = *reinterpret_cast<const short8*>(
                wf + (size_t)col * DD + k);
            acc[t] = __builtin_amdgcn_mfma_f32_16x16x32_f16(af, bf, acc[t], 0, 0, 0);
        }
    }

    const int rg = (lane >> 4) * 4;
    #pragma unroll
    for (int t = 0; t < 8; ++t) {
        const int c  = t * 16 + la;
        const float bb = b[c];
        #pragma unroll
        for (int j = 0; j < 4; ++j) {
            const int rl = m0 + rg + j;
            const int rr = r0 + rl;
            if (rr < NN) {
                out[(size_t)rr * DD + c] =
                    theta * (acc[t][j] + bb) + mtheta * sS[rl][c];
            }
        }
    }
}

// ---------------------------------------------------------------------------
// Tier1 (round-8 proven): f16 gather agg WITH h0 blend -> fp32 io.
// ---------------------------------------------------------------------------
__global__ __launch_bounds__(256, 8) void agg_f16(
    const ushort* __restrict__ hh, const float* __restrict__ h0,
    const int* __restrict__ edge_col, const float* __restrict__ edge_vals,
    const int* __restrict__ rp, float* __restrict__ io)
{
    const int wave = threadIdx.x >> 6;
    const int lane = threadIdx.x & 63;
    const int g    = lane >> 4;
    const int li   = lane & 15;
    const int r    = blockIdx.x * 4 + wave;
    if (r >= NN) return;

    const int e0 = rp[r], e1 = rp[r + 1];

    h2 a0 = {0, 0}, a1 = {0, 0}, a2 = {0, 0}, a3 = {0, 0};

    for (int eb = e0; eb < e1; eb += 16) {
        #pragma unroll
        for (int u = 0; u < 4; ++u) {
            const int e  = eb + u * 4 + g;
            const int ee = min(e, e1 - 1);
            const int   c = edge_col[ee];
            const float v = (e < e1) ? edge_vals[ee] : 0.0f;
            const uint4 hv = *reinterpret_cast<const uint4*>(
                hh + (size_t)c * DD + li * 8);
            const _Float16 vh = (_Float16)v;
            const h2 vv = {vh, vh};
            a0 += as_h2(hv.x) * vv;
            a1 += as_h2(hv.y) * vv;
            a2 += as_h2(hv.z) * vv;
            a3 += as_h2(hv.w) * vv;
        }
    }

    float acc[8];
    acc[0] = (float)a0.x; acc[1] = (float)a0.y;
    acc[2] = (float)a1.x; acc[3] = (float)a1.y;
    acc[4] = (float)a2.x; acc[5] = (float)a2.y;
    acc[6] = (float)a3.x; acc[7] = (float)a3.y;

    #pragma unroll
    for (int j = 0; j < 8; ++j) {
        acc[j] += __shfl_xor(acc[j], 16);
        acc[j] += __shfl_xor(acc[j], 32);
    }

    if (g == 0) {
        const float4 h0a = *reinterpret_cast<const float4*>(
            h0 + (size_t)r * DD + li * 8);
        const float4 h0b = *reinterpret_cast<const float4*>(
            h0 + (size_t)r * DD + li * 8 + 4);
        float4 oa, ob;
        oa.x = fmaf(1.0f - ALPHA, acc[0], ALPHA * h0a.x);
        oa.y = fmaf(1.0f - ALPHA, acc[1], ALPHA * h0a.y);
        oa.z = fmaf(1.0f - ALPHA, acc[2], ALPHA * h0a.z);
        oa.w = fmaf(1.0f - ALPHA, acc[3], ALPHA * h0a.w);
        ob.x = fmaf(1.0f - ALPHA, acc[4], ALPHA * h0b.x);
        ob.y = fmaf(1.0f - ALPHA, acc[5], ALPHA * h0b.y);
        ob.z = fmaf(1.0f - ALPHA, acc[6], ALPHA * h0b.z);
        ob.w = fmaf(1.0f - ALPHA, acc[7], ALPHA * h0b.w);
        *reinterpret_cast<float4*>(io + (size_t)r * DD + li * 8)     = oa;
        *reinterpret_cast<float4*>(io + (size_t)r * DD + li * 8 + 4) = ob;
    }
}

// ---------------------------------------------------------------------------
// Tier1 (round-6 proven): bf16 MFMA linear+blend, in place on io.
// ---------------------------------------------------------------------------
__global__ __launch_bounds__(256, 3) void lin_mfma(
    float* io, const ushort* __restrict__ wb, const float* __restrict__ b,
    const int* __restrict__ lptr)
{
    __shared__ float  sS[64][132];
    __shared__ ushort sA[64][136];

    const int tid = threadIdx.x;
    const int r0  = blockIdx.x * 64;

    const int lv = *lptr;
    const float theta  = logf(BETA / (float)lv + 1.0f);
    const float mtheta = 1.0f - theta;

    for (int idx = tid; idx < 64 * 16; idx += 256) {
        const int row = idx >> 4;
        const int c8  = (idx & 15) * 8;
        const int rr  = r0 + row;
        float4 v0 = make_float4(0.f, 0.f, 0.f, 0.f);
        float4 v1 = make_float4(0.f, 0.f, 0.f, 0.f);
        if (rr < NN) {
            v0 = *reinterpret_cast<const float4*>(io + (size_t)rr * DD + c8);
            v1 = *reinterpret_cast<const float4*>(io + (size_t)rr * DD + c8 + 4);
        }
        *reinterpret_cast<float4*>(&sS[row][c8])     = v0;
        *reinterpret_cast<float4*>(&sS[row][c8 + 4]) = v1;
        uint4 pk;
        pk.x = pkbf(v0.x, v0.y);
        pk.y = pkbf(v0.z, v0.w);
        pk.z = pkbf(v1.x, v1.y);
        pk.w = pkbf(v1.z, v1.w);
        *reinterpret_cast<uint4*>(&sA[row][c8]) = pk;
    }
    __syncthreads();

    const int wave = tid >> 6;
    const int lane = tid & 63;
    const int m0   = wave * 16;
    const int la   = lane & 15;
    const int k0   = (lane >> 4) * 8;

    floatx4 acc[8];
    #pragma unroll
    for (int t = 0; t < 8; ++t) acc[t] = (floatx4){0.f, 0.f, 0.f, 0.f};

    #pragma unroll
    for (int s = 0; s < 4; ++s) {
        const int k = s * 32 + k0;
        const short8 af = *reinterpret_cast<const short8*>(&sA[m0 + la][k]);
        #pragma unroll
        for (int t = 0; t < 8; ++t) {
            const int col = t * 16 + la;
            const short8 bf = *reinterpret_cast<const short8*>(
                wb + (size_t)col * DD + k);
            acc[t] = __builtin_amdgcn_mfma_f32_16x16x32_bf16(af, bf, acc[t], 0, 0, 0);
        }
    }

    const int rg = (lane >> 4) * 4;
    #pragma unroll
    for (int t = 0; t < 8; ++t) {
        const int c  = t * 16 + la;
        const float bb = b[c];
        #pragma unroll
        for (int j = 0; j < 4; ++j) {
            const int rl = m0 + rg + j;
            const int rr = r0 + rl;
            if (rr < NN) {
                const float sup = sS[rl][c];
                io[(size_t)rr * DD + c] =
                    theta * (acc[t][j] + bb) + mtheta * sup;
            }
        }
    }
}

// ---------------------------------------------------------------------------
// Tier0 fallback: fp32 aggregation + fp32-vector linear.
// ---------------------------------------------------------------------------
__global__ __launch_bounds__(256, 6) void agg_fp32(
    const float* __restrict__ h, const float* __restrict__ h0,
    const int* __restrict__ edge_col, const float* __restrict__ edge_vals,
    const int* __restrict__ rp, float* __restrict__ io)
{
    const int wave = threadIdx.x >> 6;
    const int lane = threadIdx.x & 63;
    const int p    = lane >> 5;
    const int li   = lane & 31;
    const int r    = blockIdx.x * 4 + wave;
    if (r >= NN) return;

    const int e0 = rp[r], e1 = rp[r + 1];

    float4 A[4];
    #pragma unroll
    for (int u = 0; u < 4; ++u) A[u] = make_float4(0.f, 0.f, 0.f, 0.f);

    for (int eb = e0; eb < e1; eb += 8) {
        #pragma unroll
        for (int u = 0; u < 4; ++u) {
            const int e  = eb + 2 * u + p;
            const int ee = min(e, e1 - 1);
            const int   c = edge_col[ee];
            const float v = (e < e1) ? edge_vals[ee] : 0.0f;
            const float4 hv =
                *reinterpret_cast<const float4*>(h + (size_t)c * DD + li * 4);
            A[u].x = fmaf(v, hv.x, A[u].x);
            A[u].y = fmaf(v, hv.y, A[u].y);
            A[u].z = fmaf(v, hv.z, A[u].z);
            A[u].w = fmaf(v, hv.w, A[u].w);
        }
    }
    float4 s;
    s.x = (A[0].x + A[1].x) + (A[2].x + A[3].x);
    s.y = (A[0].y + A[1].y) + (A[2].y + A[3].y);
    s.z = (A[0].z + A[1].z) + (A[2].z + A[3].z);
    s.w = (A[0].w + A[1].w) + (A[2].w + A[3].w);
    s.x += __shfl_xor(s.x, 32);
    s.y += __shfl_xor(s.y, 32);
    s.z += __shfl_xor(s.z, 32);
    s.w += __shfl_xor(s.w, 32);

    if (p == 0) {
        const float4 h0v =
            *reinterpret_cast<const float4*>(h0 + (size_t)r * DD + li * 4);
        float4 sup;
        sup.x = fmaf(1.0f - ALPHA, s.x, ALPHA * h0v.x);
        sup.y = fmaf(1.0f - ALPHA, s.y, ALPHA * h0v.y);
        sup.z = fmaf(1.0f - ALPHA, s.z, ALPHA * h0v.z);
        sup.w = fmaf(1.0f - ALPHA, s.w, ALPHA * h0v.w);
        *reinterpret_cast<float4*>(io + (size_t)r * DD + li * 4) = sup;
    }
}

#define RPB 64
#define SPAD 132
#define WPAD 136

__global__ __launch_bounds__(512, 4) void lin_kernel(
    float* io, const float* __restrict__ W, const float* __restrict__ b,
    const int* __restrict__ lptr)
{
    __shared__ float sS[RPB][SPAD];
    __shared__ __hip_bfloat16 sWt[DD][WPAD];

    const int tid = threadIdx.x;
    const int r0  = blockIdx.x * RPB;
    const int tr  = tid >> 4;
    const int tc  = tid & 15;

    const int lv = *lptr;
    const float theta  = logf(BETA / (float)lv + 1.0f);
    const float mtheta = 1.0f - theta;

    for (int i = tid * 4; i < DD * DD; i += 512 * 4) {
        const float4 w4 = *reinterpret_cast<const float4*>(W + i);
        const int o = i >> 7;
        const int k = i & 127;
        sWt[k + 0][o] = __float2bfloat16(w4.x);
        sWt[k + 1][o] = __float2bfloat16(w4.y);
        sWt[k + 2][o] = __float2bfloat16(w4.z);
        sWt[k + 3][o] = __float2bfloat16(w4.w);
    }

    for (int idx = tid; idx < RPB * 32; idx += 512) {
        const int row = idx >> 5;
        const int q   = idx & 31;
        const int rr  = r0 + row;
        const float4 v = (rr < NN)
            ? *reinterpret_cast<const float4*>(io + (size_t)rr * DD + q * 4)
            : make_float4(0.f, 0.f, 0.f, 0.f);
        *reinterpret_cast<float4*>(&sS[row][q * 4]) = v;
    }
    __syncthreads();

    float acc[2][8];
    #pragma unroll
    for (int i = 0; i < 2; ++i)
        #pragma unroll
        for (int j = 0; j < 8; ++j) acc[i][j] = 0.f;

    for (int k = 0; k < DD; k += 4) {
        const float4 a0 = *reinterpret_cast<const float4*>(&sS[tr * 2 + 0][k]);
        const float4 a1 = *reinterpret_cast<const float4*>(&sS[tr * 2 + 1][k]);
        const float aa0[4] = {a0.x, a0.y, a0.z, a0.w};
        const float aa1[4] = {a1.x, a1.y, a1.z, a1.w};
        #pragma unroll
        for (int kk = 0; kk < 4; ++kk) {
            const uint4 wr = *reinterpret_cast<const uint4*>(&sWt[k + kk][tc * 8]);
            float w[8];
            w[0] = bf16lo(wr.x); w[1] = bf16hi(wr.x);
            w[2] = bf16lo(wr.y); w[3] = bf16hi(wr.y);
            w[4] = bf16lo(wr.z); w[5] = bf16hi(wr.z);
            w[6] = bf16lo(wr.w); w[7] = bf16hi(wr.w);
            #pragma unroll
            for (int j = 0; j < 8; ++j) {
                acc[0][j] = fmaf(aa0[kk], w[j], acc[0][j]);
                acc[1][j] = fmaf(aa1[kk], w[j], acc[1][j]);
            }
        }
    }

    #pragma unroll
    for (int i = 0; i < 2; ++i) {
        const int ri = tr * 2 + i;
        const int rr = r0 + ri;
        if (rr >= NN) continue;
        #pragma unroll
        for (int j4 = 0; j4 < 2; ++j4) {
            const int cc = tc * 8 + j4 * 4;
            const float4 bv  = *reinterpret_cast<const float4*>(&b[cc]);
            const float4 sup = *reinterpret_cast<const float4*>(&sS[ri][cc]);
            float4 o4;
            o4.x = theta * (acc[i][j4 * 4 + 0] + bv.x) + mtheta * sup.x;
            o4.y = theta * (acc[i][j4 * 4 + 1] + bv.y) + mtheta * sup.y;
            o4.z = theta * (acc[i][j4 * 4 + 2] + bv.z) + mtheta * sup.z;
            o4.w = theta * (acc[i][j4 * 4 + 3] + bv.w) + mtheta * sup.w;
            *reinterpret_cast<float4*>(io + (size_t)rr * DD + cc) = o4;
        }
    }
}

extern "C" void kernel_launch(void* const* d_in, const int* in_sizes, int n_in,
                              void* d_out, int out_size, void* d_ws, size_t ws_size,
                              hipStream_t stream) {
    const float* h         = (const float*)d_in[0];
    const float* h0        = (const float*)d_in[1];
    const int*   edge_row  = (const int*)d_in[2];
    const int*   edge_col  = (const int*)d_in[3];
    const float* edge_vals = (const float*)d_in[4];
    const float* W         = (const float*)d_in[5];
    const float* b         = (const float*)d_in[6];
    const int*   lptr      = (const int*)d_in[7];
    const int E = in_sizes[2];

    // ws layout: rp(256KB) | hh f16 h (12.8MB) | wf f16 W (32KB) |
    //            wbf bf16 W (32KB) | hib f16 hi (12.8MB, tier2 only)
    char* wsb = (char*)d_ws;
    const size_t sz_hh = (size_t)NN * DD * sizeof(ushort);
    const size_t sz_w  = (size_t)DD * DD * sizeof(ushort);
    int*    rp  = (int*)wsb;
    ushort* hh  = (ushort*)(wsb + (1 << 18));
    ushort* wf  = (ushort*)(wsb + (1 << 18) + sz_hh);
    ushort* wbf = (ushort*)(wsb + (1 << 18) + sz_hh + sz_w);
    ushort* hib = (ushort*)(wsb + (1 << 18) + sz_hh + 2 * sz_w);
    float*  io  = (float*)d_out;

    const size_t need1 = (size_t)(1 << 18) + sz_hh + 2 * sz_w;
    const size_t need2 = need1 + sz_hh;

    const int nT = (NN * DD / 8 > E + 1) ? NN * DD / 8 : E + 1;
    const int gridP = (nT + 255) / 256;

    if (ws_size >= need2) {
        prep_kernel<<<gridP, 256, 0, stream>>>(edge_row, E, rp, h, hh, W, wf, wbf);
        agg2<<<(NN + 3) / 4, 256, 0, stream>>>(hh, edge_col, edge_vals, rp, hib);
        lin2<<<(NN + 63) / 64, 256, 0, stream>>>(hib, h0, wf, b, lptr, io);
    } else if (ws_size >= need1) {
        prep_kernel<<<gridP, 256, 0, stream>>>(edge_row, E, rp, h, hh, W, wf, wbf);
        agg_f16<<<(NN + 3) / 4, 256, 0, stream>>>(hh, h0, edge_col, edge_vals, rp, io);
        lin_mfma<<<(NN + 63) / 64, 256, 0, stream>>>(io, wbf, b, lptr);
    } else {
        prep_kernel<<<gridP, 256, 0, stream>>>(edge_row, E, rp, h,
                                               nullptr, W, nullptr, nullptr);
        agg_fp32<<<(NN + 3) / 4, 256, 0, stream>>>(h, h0, edge_col, edge_vals, rp, io);
        lin_kernel<<<(NN + RPB - 1) / RPB, 512, 0, stream>>>(io, W, b, lptr);
    }
}

// Round 10
// 64.002 us; speedup vs baseline: 1.4832x; 1.1937x over previous
//
#include <hip/hip_runtime.h>
#include <hip/hip_bf16.h>
#include <math.h>

#define NN 50000
#define DD 128
#define ALPHA 0.1f
#define BETA 0.5f

typedef __attribute__((ext_vector_type(8))) short short8;   // 8x16b MFMA frag
typedef __attribute__((ext_vector_type(4))) float floatx4;  // f32x4 accum
typedef _Float16 h2 __attribute__((ext_vector_type(2)));    // packed f16 pair

__device__ __forceinline__ float bf16lo(unsigned u) {
    return __uint_as_float(u << 16);
}
__device__ __forceinline__ float bf16hi(unsigned u) {
    return __uint_as_float(u & 0xffff0000u);
}
__device__ __forceinline__ unsigned pkh(float a, float b) {
    h2 p = {(_Float16)a, (_Float16)b};
    return __builtin_bit_cast(unsigned, p);
}
__device__ __forceinline__ h2 as_h2(unsigned u) {
    return __builtin_bit_cast(h2, u);
}

// ---------------------------------------------------------------------------
// Kernel 1: prep = rowptr + h->f16 + W->f16.
// ---------------------------------------------------------------------------
__global__ __launch_bounds__(256) void prep_kernel(
    const int* __restrict__ edge_row, int E, int* __restrict__ rp,
    const float* __restrict__ h, ushort* __restrict__ hh,
    const float* __restrict__ W, ushort* __restrict__ wf)
{
    const int t = blockIdx.x * 256 + threadIdx.x;

    if (hh != nullptr && t < NN * DD / 8) {
        const float4 v0 = *reinterpret_cast<const float4*>(h + (size_t)t * 8);
        const float4 v1 = *reinterpret_cast<const float4*>(h + (size_t)t * 8 + 4);
        uint4 o;
        o.x = pkh(v0.x, v0.y);
        o.y = pkh(v0.z, v0.w);
        o.z = pkh(v1.x, v1.y);
        o.w = pkh(v1.z, v1.w);
        *reinterpret_cast<uint4*>(hh + (size_t)t * 8) = o;
    }

    if (wf != nullptr && t < DD * DD / 4) {
        const float4 v = *reinterpret_cast<const float4*>(W + (size_t)t * 4);
        uint2 of;
        of.x = pkh(v.x, v.y);
        of.y = pkh(v.z, v.w);
        *reinterpret_cast<uint2*>(wf + (size_t)t * 4) = of;
    }

    if (t <= E) {
        if (t == 0) {
            int r0 = edge_row[0];
            for (int r = 0; r <= r0; ++r) rp[r] = 0;
        } else if (t == E) {
            int rl = edge_row[E - 1];
            for (int r = rl + 1; r <= NN; ++r) rp[r] = E;
        } else {
            int rprev = edge_row[t - 1];
            int rcur  = edge_row[t];
            for (int r = rprev + 1; r <= rcur; ++r) rp[r] = t;
        }
    }
}

// ---------------------------------------------------------------------------
// Kernel 2: FUSED agg + MFMA linear + blend on a 16-row micro-tile.
// 256 threads (4 waves); wave w aggregates rows w*4..w*4+3 (f16 gather,
// 16 edges / 4 independent gathers in flight), blends h0, stages sup into
// LDS (sS fp32 for epilogue + sA f16 for MFMA A). Barrier. MFMA phase:
// wave w computes cols w*32..w*32+31 (2 col-tiles x 4 K-steps, B-frags
// straight from L2-hot f16 W, row-major [out][in] -> k contiguous).
// C-layout (HW-verified r6): col=lane&15, row=(lane>>4)*4+reg.
// LDS = 16*132*4 + 16*136*2 = 12.8KB. NN = 3125*16 exactly -> no bounds.
// ---------------------------------------------------------------------------
__global__ __launch_bounds__(256, 6) void fused16(
    const ushort* __restrict__ hh, const float* __restrict__ h0,
    const int* __restrict__ edge_col, const float* __restrict__ edge_vals,
    const int* __restrict__ rp, const ushort* __restrict__ wf,
    const float* __restrict__ b, const int* __restrict__ lptr,
    float* __restrict__ out)
{
    __shared__ float  sS[16][132];
    __shared__ ushort sA[16][136];

    const int tid  = threadIdx.x;
    const int wave = tid >> 6;      // 0..3
    const int lane = tid & 63;
    const int g    = lane >> 4;     // edge slot 0..3
    const int li   = lane & 15;     // feature octet li*8..+7
    const int r0   = blockIdx.x * 16;

    const int lv = *lptr;
    const float theta  = logf(BETA / (float)lv + 1.0f);
    const float mtheta = 1.0f - theta;

    // ---------------- Phase A: aggregate 4 rows per wave ----------------
    #pragma unroll 1
    for (int q = 0; q < 4; ++q) {
        const int ri = wave * 4 + q;
        const int r  = r0 + ri;
        const int e0 = rp[r], e1 = rp[r + 1];

        h2 a0 = {0, 0}, a1 = {0, 0}, a2 = {0, 0}, a3 = {0, 0};

        for (int eb = e0; eb < e1; eb += 16) {
            #pragma unroll
            for (int u = 0; u < 4; ++u) {
                const int e  = eb + u * 4 + g;
                const int ee = min(e, e1 - 1);
                const int   c = edge_col[ee];
                const float v = (e < e1) ? edge_vals[ee] : 0.0f;
                const uint4 hv = *reinterpret_cast<const uint4*>(
                    hh + (size_t)c * DD + li * 8);
                const _Float16 vh = (_Float16)v;
                const h2 vv = {vh, vh};
                a0 += as_h2(hv.x) * vv;
                a1 += as_h2(hv.y) * vv;
                a2 += as_h2(hv.z) * vv;
                a3 += as_h2(hv.w) * vv;
            }
        }

        float acc[8];
        acc[0] = (float)a0.x; acc[1] = (float)a0.y;
        acc[2] = (float)a1.x; acc[3] = (float)a1.y;
        acc[4] = (float)a2.x; acc[5] = (float)a2.y;
        acc[6] = (float)a3.x; acc[7] = (float)a3.y;

        #pragma unroll
        for (int j = 0; j < 8; ++j) {
            acc[j] += __shfl_xor(acc[j], 16);
            acc[j] += __shfl_xor(acc[j], 32);
        }

        if (g == 0) {
            const float4 h0a = *reinterpret_cast<const float4*>(
                h0 + (size_t)r * DD + li * 8);
            const float4 h0b = *reinterpret_cast<const float4*>(
                h0 + (size_t)r * DD + li * 8 + 4);
            float sup[8];
            sup[0] = fmaf(1.0f - ALPHA, acc[0], ALPHA * h0a.x);
            sup[1] = fmaf(1.0f - ALPHA, acc[1], ALPHA * h0a.y);
            sup[2] = fmaf(1.0f - ALPHA, acc[2], ALPHA * h0a.z);
            sup[3] = fmaf(1.0f - ALPHA, acc[3], ALPHA * h0a.w);
            sup[4] = fmaf(1.0f - ALPHA, acc[4], ALPHA * h0b.x);
            sup[5] = fmaf(1.0f - ALPHA, acc[5], ALPHA * h0b.y);
            sup[6] = fmaf(1.0f - ALPHA, acc[6], ALPHA * h0b.z);
            sup[7] = fmaf(1.0f - ALPHA, acc[7], ALPHA * h0b.w);
            *reinterpret_cast<float4*>(&sS[ri][li * 8]) =
                make_float4(sup[0], sup[1], sup[2], sup[3]);
            *reinterpret_cast<float4*>(&sS[ri][li * 8 + 4]) =
                make_float4(sup[4], sup[5], sup[6], sup[7]);
            uint4 pk;
            pk.x = pkh(sup[0], sup[1]);
            pk.y = pkh(sup[2], sup[3]);
            pk.z = pkh(sup[4], sup[5]);
            pk.w = pkh(sup[6], sup[7]);
            *reinterpret_cast<uint4*>(&sA[ri][li * 8]) = pk;
        }
    }
    __syncthreads();

    // ---------------- Phase B: MFMA linear, cols wave*32..+31 ----------------
    const int la = lane & 15;
    const int k0 = (lane >> 4) * 8;

    floatx4 facc[2];
    facc[0] = (floatx4){0.f, 0.f, 0.f, 0.f};
    facc[1] = (floatx4){0.f, 0.f, 0.f, 0.f};

    #pragma unroll
    for (int s = 0; s < 4; ++s) {
        const int k = s * 32 + k0;
        const short8 af = *reinterpret_cast<const short8*>(&sA[la][k]);
        #pragma unroll
        for (int t = 0; t < 2; ++t) {
            const int col = wave * 32 + t * 16 + la;
            const short8 bf = *reinterpret_cast<const short8*>(
                wf + (size_t)col * DD + k);
            facc[t] = __builtin_amdgcn_mfma_f32_16x16x32_f16(af, bf, facc[t], 0, 0, 0);
        }
    }

    // ---------------- epilogue: blend + store ----------------
    const int rg = (lane >> 4) * 4;
    #pragma unroll
    for (int t = 0; t < 2; ++t) {
        const int c  = wave * 32 + t * 16 + la;
        const float bb = b[c];
        #pragma unroll
        for (int j = 0; j < 4; ++j) {
            const int rl = rg + j;
            out[(size_t)(r0 + rl) * DD + c] =
                theta * (facc[t][j] + bb) + mtheta * sS[rl][c];
        }
    }
}

// ---------------------------------------------------------------------------
// Tier0 fallback (ws too small): fp32 aggregation + fp32-vector linear.
// ---------------------------------------------------------------------------
__global__ __launch_bounds__(256, 6) void agg_fp32(
    const float* __restrict__ h, const float* __restrict__ h0,
    const int* __restrict__ edge_col, const float* __restrict__ edge_vals,
    const int* __restrict__ rp, float* __restrict__ io)
{
    const int wave = threadIdx.x >> 6;
    const int lane = threadIdx.x & 63;
    const int p    = lane >> 5;
    const int li   = lane & 31;
    const int r    = blockIdx.x * 4 + wave;
    if (r >= NN) return;

    const int e0 = rp[r], e1 = rp[r + 1];

    float4 A[4];
    #pragma unroll
    for (int u = 0; u < 4; ++u) A[u] = make_float4(0.f, 0.f, 0.f, 0.f);

    for (int eb = e0; eb < e1; eb += 8) {
        #pragma unroll
        for (int u = 0; u < 4; ++u) {
            const int e  = eb + 2 * u + p;
            const int ee = min(e, e1 - 1);
            const int   c = edge_col[ee];
            const float v = (e < e1) ? edge_vals[ee] : 0.0f;
            const float4 hv =
                *reinterpret_cast<const float4*>(h + (size_t)c * DD + li * 4);
            A[u].x = fmaf(v, hv.x, A[u].x);
            A[u].y = fmaf(v, hv.y, A[u].y);
            A[u].z = fmaf(v, hv.z, A[u].z);
            A[u].w = fmaf(v, hv.w, A[u].w);
        }
    }
    float4 s;
    s.x = (A[0].x + A[1].x) + (A[2].x + A[3].x);
    s.y = (A[0].y + A[1].y) + (A[2].y + A[3].y);
    s.z = (A[0].z + A[1].z) + (A[2].z + A[3].z);
    s.w = (A[0].w + A[1].w) + (A[2].w + A[3].w);
    s.x += __shfl_xor(s.x, 32);
    s.y += __shfl_xor(s.y, 32);
    s.z += __shfl_xor(s.z, 32);
    s.w += __shfl_xor(s.w, 32);

    if (p == 0) {
        const float4 h0v =
            *reinterpret_cast<const float4*>(h0 + (size_t)r * DD + li * 4);
        float4 sup;
        sup.x = fmaf(1.0f - ALPHA, s.x, ALPHA * h0v.x);
        sup.y = fmaf(1.0f - ALPHA, s.y, ALPHA * h0v.y);
        sup.z = fmaf(1.0f - ALPHA, s.z, ALPHA * h0v.z);
        sup.w = fmaf(1.0f - ALPHA, s.w, ALPHA * h0v.w);
        *reinterpret_cast<float4*>(io + (size_t)r * DD + li * 4) = sup;
    }
}

#define RPB 64
#define SPAD 132
#define WPAD 136

__global__ __launch_bounds__(512, 4) void lin_kernel(
    float* io, const float* __restrict__ W, const float* __restrict__ b,
    const int* __restrict__ lptr)
{
    __shared__ float sS[RPB][SPAD];
    __shared__ __hip_bfloat16 sWt[DD][WPAD];

    const int tid = threadIdx.x;
    const int r0  = blockIdx.x * RPB;
    const int tr  = tid >> 4;
    const int tc  = tid & 15;

    const int lv = *lptr;
    const float theta  = logf(BETA / (float)lv + 1.0f);
    const float mtheta = 1.0f - theta;

    for (int i = tid * 4; i < DD * DD; i += 512 * 4) {
        const float4 w4 = *reinterpret_cast<const float4*>(W + i);
        const int o = i >> 7;
        const int k = i & 127;
        sWt[k + 0][o] = __float2bfloat16(w4.x);
        sWt[k + 1][o] = __float2bfloat16(w4.y);
        sWt[k + 2][o] = __float2bfloat16(w4.z);
        sWt[k + 3][o] = __float2bfloat16(w4.w);
    }

    for (int idx = tid; idx < RPB * 32; idx += 512) {
        const int row = idx >> 5;
        const int q   = idx & 31;
        const int rr  = r0 + row;
        const float4 v = (rr < NN)
            ? *reinterpret_cast<const float4*>(io + (size_t)rr * DD + q * 4)
            : make_float4(0.f, 0.f, 0.f, 0.f);
        *reinterpret_cast<float4*>(&sS[row][q * 4]) = v;
    }
    __syncthreads();

    float acc[2][8];
    #pragma unroll
    for (int i = 0; i < 2; ++i)
        #pragma unroll
        for (int j = 0; j < 8; ++j) acc[i][j] = 0.f;

    for (int k = 0; k < DD; k += 4) {
        const float4 a0 = *reinterpret_cast<const float4*>(&sS[tr * 2 + 0][k]);
        const float4 a1 = *reinterpret_cast<const float4*>(&sS[tr * 2 + 1][k]);
        const float aa0[4] = {a0.x, a0.y, a0.z, a0.w};
        const float aa1[4] = {a1.x, a1.y, a1.z, a1.w};
        #pragma unroll
        for (int kk = 0; kk < 4; ++kk) {
            const uint4 wr = *reinterpret_cast<const uint4*>(&sWt[k + kk][tc * 8]);
            float w[8];
            w[0] = bf16lo(wr.x); w[1] = bf16hi(wr.x);
            w[2] = bf16lo(wr.y); w[3] = bf16hi(wr.y);
            w[4] = bf16lo(wr.z); w[5] = bf16hi(wr.z);
            w[6] = bf16lo(wr.w); w[7] = bf16hi(wr.w);
            #pragma unroll
            for (int j = 0; j < 8; ++j) {
                acc[0][j] = fmaf(aa0[kk], w[j], acc[0][j]);
                acc[1][j] = fmaf(aa1[kk], w[j], acc[1][j]);
            }
        }
    }

    #pragma unroll
    for (int i = 0; i < 2; ++i) {
        const int ri = tr * 2 + i;
        const int rr = r0 + ri;
        if (rr >= NN) continue;
        #pragma unroll
        for (int j4 = 0; j4 < 2; ++j4) {
            const int cc = tc * 8 + j4 * 4;
            const float4 bv  = *reinterpret_cast<const float4*>(&b[cc]);
            const float4 sup = *reinterpret_cast<const float4*>(&sS[ri][cc]);
            float4 o4;
            o4.x = theta * (acc[i][j4 * 4 + 0] + bv.x) + mtheta * sup.x;
            o4.y = theta * (acc[i][j4 * 4 + 1] + bv.y) + mtheta * sup.y;
            o4.z = theta * (acc[i][j4 * 4 + 2] + bv.z) + mtheta * sup.z;
            o4.w = theta * (acc[i][j4 * 4 + 3] + bv.w) + mtheta * sup.w;
            *reinterpret_cast<float4*>(io + (size_t)rr * DD + cc) = o4;
        }
    }
}

extern "C" void kernel_launch(void* const* d_in, const int* in_sizes, int n_in,
                              void* d_out, int out_size, void* d_ws, size_t ws_size,
                              hipStream_t stream) {
    const float* h         = (const float*)d_in[0];
    const float* h0        = (const float*)d_in[1];
    const int*   edge_row  = (const int*)d_in[2];
    const int*   edge_col  = (const int*)d_in[3];
    const float* edge_vals = (const float*)d_in[4];
    const float* W         = (const float*)d_in[5];
    const float* b         = (const float*)d_in[6];
    const int*   lptr      = (const int*)d_in[7];
    const int E = in_sizes[2];

    // ws layout: rp (256KB) | hh f16 h (12.8MB) | wf f16 W (32KB)
    char* wsb = (char*)d_ws;
    const size_t sz_hh = (size_t)NN * DD * sizeof(ushort);
    const size_t sz_w  = (size_t)DD * DD * sizeof(ushort);
    int*    rp = (int*)wsb;
    ushort* hh = (ushort*)(wsb + (1 << 18));
    ushort* wf = (ushort*)(wsb + (1 << 18) + sz_hh);
    float*  io = (float*)d_out;

    const size_t need = (size_t)(1 << 18) + sz_hh + sz_w;

    const int nT = (NN * DD / 8 > E + 1) ? NN * DD / 8 : E + 1;
    const int gridP = (nT + 255) / 256;

    if (ws_size >= need) {
        prep_kernel<<<gridP, 256, 0, stream>>>(edge_row, E, rp, h, hh, W, wf);
        fused16<<<NN / 16, 256, 0, stream>>>(
            hh, h0, edge_col, edge_vals, rp, wf, b, lptr, io);
    } else {
        prep_kernel<<<gridP, 256, 0, stream>>>(edge_row, E, rp, h,
                                               nullptr, W, nullptr);
        agg_fp32<<<(NN + 3) / 4, 256, 0, stream>>>(h, h0, edge_col, edge_vals, rp, io);
        lin_kernel<<<(NN + RPB - 1) / RPB, 512, 0, stream>>>(io, W, b, lptr);
    }
}